// Round 9
// baseline (1447.653 us; speedup 1.0000x reference)
//
#include <hip/hip_runtime.h>
#include <hip/hip_bf16.h>

typedef unsigned int u32;
typedef unsigned short u16;
typedef short short8 __attribute__((ext_vector_type(8)));
typedef float f32x4 __attribute__((ext_vector_type(4)));

#define R_ 32
#define KEYS_PER_B 2048     // 4 wavegroups * 32 relations * 16 rows
#define SORT_STRIDE 1024    // per-tile slots in sorted[] (mean ~768, +9 sigma)
#define CAP 16              // per-wave per-relation buffered edge gathers
#define MAXU 16384          // max unique scored nodes (2*T)
#define NSPLIT 4            // relation-group split
#define NRG 8               // relations per group (R_/NSPLIT)
#define GRID 1024           // co-resident by construction: 4 blocks/CU x 256 CU

static __device__ __forceinline__ u16 f2bf(float f) {
  u32 u = __float_as_uint(f);
  u = (u + 0x7FFFu + ((u >> 16) & 1u)) >> 16;   // RNE
  return (u16)u;
}
static __device__ __forceinline__ u32 pk2(float a, float b) {
  __hip_bfloat162 h2 = __float22bfloat162_rn(make_float2(a, b));
  union { __hip_bfloat162 h; u32 u; } cv; cv.h = h2; return cv.u;
}

// key over COMPACT target ids: (tile, wavegroup-of-16, relation, row-in-group)
static __device__ __forceinline__ int sort_key(int ct, int r) {
  return (ct >> 6) * KEYS_PER_B + ((ct >> 4) & 3) * 512 + r * 16 + (ct & 15);
}

// ---- software grid barrier (capture-safe cooperative substitute) ----
// bar[slot] is memset to -1 each launch; after nBlk arrivals it equals nBlk-1.
// All GRID blocks are guaranteed co-resident (launch_bounds(256,4): VGPR<=128,
// LDS 32KB*4=128KB<=160KB -> 4 blocks/CU x 256 CU = GRID). Device-scope
// atomics + agent fences handle cross-XCD visibility (L1 invalidate).
static __device__ __forceinline__ void gsync(int* bar, int slot, int nBlk) {
  __syncthreads();
  __threadfence();   // release: drain this block's writes to L2
  if (threadIdx.x == 0) {
    __hip_atomic_fetch_add(bar + slot, 1, __ATOMIC_ACQ_REL, __HIP_MEMORY_SCOPE_AGENT);
    while (__hip_atomic_load(bar + slot, __ATOMIC_ACQUIRE, __HIP_MEMORY_SCOPE_AGENT)
           < nBlk - 1)
      __builtin_amdgcn_s_sleep(8);
  }
  __syncthreads();
  __threadfence();   // acquire: invalidate L1 before reading other blocks' data
}

// ======================= stage device functions =======================

static __device__ __forceinline__ void d_convert(const float* __restrict__ x,
                                                 u16* __restrict__ xb, int i, int n4) {
  if (i >= n4) return;
  const float4 f = ((const float4*)x)[i];
  u32 lo = (u32)f2bf(f.x) | ((u32)f2bf(f.y) << 16);
  u32 hi = (u32)f2bf(f.z) | ((u32)f2bf(f.w) << 16);
  ((uint2*)xb)[i] = make_uint2(lo, hi);
}

// one virtual block packs one 128x128 matrix via LDS transpose
static __device__ void d_pack(const float* __restrict__ W, const float* __restrict__ Wroot,
                              u16* __restrict__ wp, u16* __restrict__ wrootp,
                              int rr, int t, u32* lds) {
  const float* src = (rr < 32) ? (W + (size_t)rr * (128 * 128)) : Wroot;
#pragma unroll
  for (int k = 0; k < 16; ++k) {
    const int fi = k * 256 + t;
    const float4 f = ((const float4*)src)[fi];
    u32 lo = (u32)f2bf(f.x) | ((u32)f2bf(f.y) << 16);
    u32 hi = (u32)f2bf(f.z) | ((u32)f2bf(f.w) << 16);
    ((uint2*)lds)[fi] = make_uint2(lo, hi);
  }
  __syncthreads();
  const u16* l16 = (const u16*)lds;
#pragma unroll
  for (int p = 0; p < 8; ++p) {
    const int v = p * 256 + t;
    const int lane = v & 63, ks = (v >> 6) & 3, ct = v >> 8;
    const int i0 = ks * 32 + (lane >> 4) * 8;
    const int o  = ct * 16 + (lane & 15);
    u32 w01 = (u32)l16[(i0 + 0) * 128 + o] | ((u32)l16[(i0 + 1) * 128 + o] << 16);
    u32 w23 = (u32)l16[(i0 + 2) * 128 + o] | ((u32)l16[(i0 + 3) * 128 + o] << 16);
    u32 w45 = (u32)l16[(i0 + 4) * 128 + o] | ((u32)l16[(i0 + 5) * 128 + o] << 16);
    u32 w67 = (u32)l16[(i0 + 6) * 128 + o] | ((u32)l16[(i0 + 7) * 128 + o] << 16);
    u16* dst = (rr < 32) ? (wp + ((size_t)((rr * 8 + ct) * 4 + ks) * 64 + lane) * 8)
                         : (wrootp + ((size_t)((ct * 4 + ks) * 64 + lane)) * 8);
    *(uint4*)dst = make_uint4(w01, w23, w45, w67);
  }
  __syncthreads();   // lds reusable by next virtual block
}

// CAS-ticket mark/compact (map pre-filled -1, cnt pre-filled -1)
static __device__ __forceinline__ void d_mark(const int* __restrict__ head,
                                              const int* __restrict__ tail,
                                              int* __restrict__ map, int* __restrict__ inv,
                                              int* __restrict__ cnt, int i, int T) {
  if (i >= 2 * T) return;
  int n = (i < T) ? head[i] : tail[i - T];
  if (atomicCAS(map + n, -1, -2) == -1) {
    int c = atomicAdd(cnt, 1) + 1;   // cnt starts at -1 -> first ticket 0
    inv[c] = n;
    map[n] = c;
  }
}

static __device__ __forceinline__ void d_histe(const int* __restrict__ ei,
                                               const int* __restrict__ et,
                                               const int* __restrict__ map,
                                               int* __restrict__ hist, int e, int E) {
  if (e >= E) return;
  int mt = map[ei[E + e]];
  if (mt >= 0) atomicAdd(hist + sort_key(mt, et[e]), 1);
}

static __device__ void d_scan(const int* __restrict__ hist, int* __restrict__ offs,
                              int b, int t, int* wsum) {
  size_t base = (size_t)b * KEYS_PER_B + (size_t)t * 8;
  int4 a = *(const int4*)(hist + base);
  int4 c = *(const int4*)(hist + base + 4);
  int v[8] = {a.x, a.y, a.z, a.w, c.x, c.y, c.z, c.w};
  int s = 0;
#pragma unroll
  for (int i = 0; i < 8; ++i) s += v[i];
  int lane = t & 63, w = t >> 6;
  int x = s;
#pragma unroll
  for (int off = 1; off < 64; off <<= 1) {
    int y = __shfl_up(x, off);
    if (lane >= off) x += y;
  }
  if (lane == 63) wsum[w] = x;
  __syncthreads();
  int wb = 0;
  for (int i = 0; i < w; ++i) wb += wsum[i];
  int ex = wb + x - s;
  int o[8];
#pragma unroll
  for (int i = 0; i < 8; ++i) { o[i] = ex; ex += v[i]; }
  *(int4*)(offs + base) = make_int4(o[0], o[1], o[2], o[3]);
  *(int4*)(offs + base + 4) = make_int4(o[4], o[5], o[6], o[7]);
  __syncthreads();   // wsum reusable
}

static __device__ __forceinline__ void d_scat(const int* __restrict__ ei,
                                              const int* __restrict__ et,
                                              const int* __restrict__ map,
                                              int* __restrict__ offs, u32* __restrict__ sorted,
                                              int e, int E) {
  if (e >= E) return;
  int mt = map[ei[E + e]];
  if (mt < 0) return;
  int src = ei[e];
  int p = atomicAdd(offs + sort_key(mt, et[e]), 1);
  if (p < SORT_STRIDE)
    sorted[(size_t)(mt >> 6) * SORT_STRIDE + p] = (u32)src | ((u32)(mt & 63) << 16);
}

// ---- batch body: tile b (64 compact nodes) x relation group qs (8 rels) ----
#define PHASE(RR, RI, XV, EVB)                                                 \
  {                                                                            \
    const int r = (RR);                                                        \
    const int Er = __builtin_amdgcn_readlane(eAll, r);                         \
    _Pragma("unroll") for (int rr = 0; rr < 16; ++rr)                          \
        *(u32*)(aggb + (size_t)(w * 16 + rr) * 136 + 2 * lane) = 0;            \
    {                                                                          \
      const int nB = min(Er - sCur, CAP);                                      \
      int curRow = -1, rc = 0;                                                 \
      float v0 = 0.f, v1 = 0.f;                                                \
      _Pragma("unroll") for (int j = 0; j < CAP; ++j) {                        \
        if (j < nB) {                                                          \
          int e = __builtin_amdgcn_readlane((int)(EVB), j);                    \
          int tl = (e >> 16) & 63;                                             \
          if (tl != curRow) {                                                  \
            if (rc > 0) {                                                      \
              float sc = __builtin_amdgcn_rcpf((float)rc);                     \
              *(u32*)(aggb + (size_t)curRow * 136 + 2 * lane) =                \
                  pk2(v0 * sc, v1 * sc);                                       \
            }                                                                  \
            curRow = tl; v0 = 0.f; v1 = 0.f; rc = 0;                           \
          }                                                                    \
          v0 += __uint_as_float((XV)[j] << 16);                                \
          v1 += __uint_as_float((XV)[j] & 0xFFFF0000u);                        \
          ++rc;                                                                \
        }                                                                      \
      }                                                                        \
      for (int p = sCur + CAP; p < Er; ++p) {                                  \
        u32 e = srt[p];                                                        \
        u32 xvv = *(const u32*)(xb + (size_t)(e & 0xFFFFu) * 128 + 2 * lane);  \
        int tl = (int)((e >> 16) & 63);                                        \
        if (tl != curRow) {                                                    \
          if (rc > 0) {                                                        \
            float sc = __builtin_amdgcn_rcpf((float)rc);                       \
            *(u32*)(aggb + (size_t)curRow * 136 + 2 * lane) =                  \
                pk2(v0 * sc, v1 * sc);                                         \
          }                                                                    \
          curRow = tl; v0 = 0.f; v1 = 0.f; rc = 0;                             \
        }                                                                      \
        v0 += __uint_as_float(xvv << 16);                                      \
        v1 += __uint_as_float(xvv & 0xFFFF0000u);                              \
        ++rc;                                                                  \
      }                                                                        \
      if (rc > 0) {                                                            \
        float sc = __builtin_amdgcn_rcpf((float)rc);                           \
        *(u32*)(aggb + (size_t)curRow * 136 + 2 * lane) =                      \
            pk2(v0 * sc, v1 * sc);                                             \
      }                                                                        \
    }                                                                          \
    asm volatile("s_waitcnt lgkmcnt(0)" ::: "memory");                         \
    __builtin_amdgcn_sched_barrier(0);                                         \
    __builtin_amdgcn_s_barrier();                                              \
    __builtin_amdgcn_sched_barrier(0);                                         \
    short8 bfr[4][2];                                                          \
    _Pragma("unroll") for (int ks = 0; ks < 4; ++ks)                           \
      _Pragma("unroll") for (int c = 0; c < 2; ++c)                            \
        bfr[ks][c] = *(const short8*)(wp +                                     \
            ((size_t)(((r * 8 + wct0 + c) * 4 + ks) * 64 + lane)) * 8);        \
    __builtin_amdgcn_sched_barrier(0);                                         \
    if ((RI) + 2 < NRG) {                                                      \
      const int sN = __builtin_amdgcn_readlane(eAll, r + 1);                   \
      const int eN = __builtin_amdgcn_readlane(eAll, r + 2);                   \
      (EVB) = ev2;                                                             \
      const int nBn = min(eN - sN, CAP);                                       \
      _Pragma("unroll") for (int j = 0; j < CAP; ++j) {                        \
        if (j < nBn) {                                                         \
          int e = __builtin_amdgcn_readlane((int)(EVB), j);                    \
          (XV)[j] = *(const u32*)(xb + (size_t)(e & 0xFFFF) * 128 + 2 * lane); \
        }                                                                      \
      }                                                                        \
      if ((RI) + 3 < NRG) {                                                    \
        int pcn = eN + m;                                                      \
        if (pcn > clampP) pcn = clampP;                                        \
        ev2 = srt[pcn];                                                        \
      }                                                                        \
    }                                                                          \
    _Pragma("unroll") for (int ks = 0; ks < 4; ++ks) {                         \
      const int kb = ks * 32 + q * 8;                                          \
      short8 af[4];                                                            \
      _Pragma("unroll") for (int rt = 0; rt < 4; ++rt)                         \
        af[rt] = *(const short8*)(aggb + (size_t)(rt * 16 + m) * 136 + kb);    \
      _Pragma("unroll") for (int c = 0; c < 2; ++c)                            \
        _Pragma("unroll") for (int rt = 0; rt < 4; ++rt)                       \
          acc[rt][c] = __builtin_amdgcn_mfma_f32_16x16x32_bf16(                \
              af[rt], bfr[ks][c], acc[rt][c], 0, 0, 0);                        \
    }                                                                          \
    asm volatile("s_waitcnt lgkmcnt(0)" ::: "memory");                         \
    __builtin_amdgcn_sched_barrier(0);                                         \
    __builtin_amdgcn_s_barrier();                                              \
    __builtin_amdgcn_sched_barrier(0);                                         \
    sCur = Er;                                                                 \
  }

static __device__ void d_batch(
    const u16* __restrict__ xb, const u16* __restrict__ wp, const u16* __restrict__ wrootp,
    const float* __restrict__ bias, const u32* __restrict__ sorted,
    const int* __restrict__ offs, const int* __restrict__ inv,
    const int* __restrict__ cnt, float* __restrict__ h, int bb, int t, u16* aggb) {
  const int nUsed = cnt[0] + 1;    // cnt holds last ticket (init -1)
  const int qs = bb & (NSPLIT - 1);
  const int b = bb >> 2;
  const int nb = b * 64;
  if (nb >= nUsed) return;         // block-uniform: function-scope return only
  const int r0 = qs * NRG;
  const int lane = t & 63, w = t >> 6;
  const int m = lane & 15, q = lane >> 4;
  const int keyBase = b * KEYS_PER_B;
  const int wkBase = keyBase + w * 512;
  const u32* srt = sorted + (size_t)b * SORT_STRIDE;

  const int nEdge = offs[keyBase + KEYS_PER_B - 1];
  const int clampP = (nEdge > 0) ? nEdge - 1 : 0;
  const int eAll = offs[wkBase + (lane & 31) * 16 + 15];   // lane r: end of rel r
  int sCur = (w == 0 && qs == 0) ? 0 : offs[wkBase + r0 * 16 - 1];

  const int E0 = __builtin_amdgcn_readlane(eAll, r0);
  const int E1 = __builtin_amdgcn_readlane(eAll, r0 + 1);

  u32 evBufA, evBufB, ev2;
  u32 xvA[CAP], xvB[CAP];
  {
    int pc = sCur + m;
    if (pc > clampP) pc = clampP;
    evBufA = srt[pc];
  }
  {
    const int nB = min(E0 - sCur, CAP);
#pragma unroll
    for (int j = 0; j < CAP; ++j) {
      if (j < nB) {
        int e = __builtin_amdgcn_readlane((int)evBufA, j);
        xvA[j] = *(const u32*)(xb + (size_t)(e & 0xFFFF) * 128 + 2 * lane);
      }
    }
  }
  {
    int pc = E0 + m;
    if (pc > clampP) pc = clampP;
    evBufB = srt[pc];
  }
  {
    const int nB = min(E1 - E0, CAP);
#pragma unroll
    for (int j = 0; j < CAP; ++j) {
      if (j < nB) {
        int e = __builtin_amdgcn_readlane((int)evBufB, j);
        xvB[j] = *(const u32*)(xb + (size_t)(e & 0xFFFF) * 128 + 2 * lane);
      }
    }
  }
  {
    int pc = E1 + m;
    if (pc > clampP) pc = clampP;
    ev2 = srt[pc];
  }

  const short8 zero8 = {0, 0, 0, 0, 0, 0, 0, 0};
  f32x4 acc[4][2];
#pragma unroll
  for (int rt = 0; rt < 4; ++rt)
#pragma unroll
    for (int c = 0; c < 2; ++c) acc[rt][c] = (f32x4){0.f, 0.f, 0.f, 0.f};
  const int wct0 = w * 2;

  // root GEMM only in plane 0
  if (qs == 0) {
    int nodeR[4]; bool vR[4];
#pragma unroll
    for (int rt = 0; rt < 4; ++rt) {
      int crow = nb + rt * 16 + m;
      vR[rt] = crow < nUsed;
      nodeR[rt] = inv[vR[rt] ? crow : (nUsed - 1)];
    }
#pragma unroll
    for (int ks = 0; ks < 4; ++ks) {
      const int kb = ks * 32 + q * 8;
      short8 af[4];
#pragma unroll
      for (int rt = 0; rt < 4; ++rt)
        af[rt] = vR[rt] ? *(const short8*)(xb + (size_t)nodeR[rt] * 128 + kb) : zero8;
#pragma unroll
      for (int c = 0; c < 2; ++c) {
        short8 bf = *(const short8*)(wrootp + ((size_t)(((wct0 + c) * 4 + ks) * 64 + lane)) * 8);
#pragma unroll
        for (int rt = 0; rt < 4; ++rt)
          acc[rt][c] = __builtin_amdgcn_mfma_f32_16x16x32_bf16(af[rt], bf, acc[rt][c], 0, 0, 0);
      }
    }
  }

  for (int ri = 0; ri < NRG; ri += 2) {
    PHASE(r0 + ri, ri, xvA, evBufA)
    PHASE(r0 + ri + 1, ri + 1, xvB, evBufB)
  }

  // epilogue: (+bias in plane 0) store RAW partial plane
  float* hq = h + (size_t)qs * MAXU * 128;
#pragma unroll
  for (int c = 0; c < 2; ++c) {
    const int col = (wct0 + c) * 16 + m;
    const float bv = (qs == 0) ? bias[col] : 0.f;
#pragma unroll
    for (int rt = 0; rt < 4; ++rt) {
#pragma unroll
      for (int g = 0; g < 4; ++g) {
        const int row = nb + rt * 16 + q * 4 + g;
        if (row < nUsed) hq[(size_t)row * 128 + col] = acc[rt][c][g] + bv;
      }
    }
  }
}

static __device__ __forceinline__ void d_score(
    const float* __restrict__ h, const float* __restrict__ rel_emb,
    const int* __restrict__ map, const int* __restrict__ head,
    const int* __restrict__ tail, const int* __restrict__ rel,
    float* __restrict__ out, int gid, int lane, int T) {
  if (gid >= T) return;
  const int hr = map[head[gid]];
  const int tr = map[tail[gid]];
  const size_t ho = (size_t)hr * 128 + 2 * lane;
  const size_t to = (size_t)tr * 128 + 2 * lane;
  float hx = 0.f, hy = 0.f, tx = 0.f, ty = 0.f;
#pragma unroll
  for (int s = 0; s < NSPLIT; ++s) {
    const float2 a = *(const float2*)(h + (size_t)s * (MAXU * 128) + ho);
    const float2 c = *(const float2*)(h + (size_t)s * (MAXU * 128) + to);
    hx += a.x; hy += a.y; tx += c.x; ty += c.y;
  }
  hx = hx > 0.f ? hx : 0.f;
  hy = hy > 0.f ? hy : 0.f;
  tx = tx > 0.f ? tx : 0.f;
  ty = ty > 0.f ? ty : 0.f;
  const float2 r2 = *(const float2*)(rel_emb + (size_t)rel[gid] * 128 + 2 * lane);
  float s = hx * r2.x * tx + hy * r2.y * ty;
#pragma unroll
  for (int off = 32; off > 0; off >>= 1) s += __shfl_down(s, off);
  if (lane == 0) out[gid] = s;
}

// ======================= fused kernel (software grid barriers) =======================
__global__ __launch_bounds__(256, 4) void k_fused(
    const float* x, const float* W, const float* Wroot,
    u16* xb, u16* wp, u16* wrootp,
    const int* ei, const int* et,
    const int* head, const int* tail, const int* rel,
    int* map, int* inv, int* cnt, int* hist, int* offs, u32* sorted,
    const float* bias, float* h, const float* rel_emb, float* out, int* bar,
    int n4, int convNB, int histZB, int markNB, int E, int T, int NB2) {
  __shared__ u32 shm[8192];   // 32 KB: pack transpose / aggb / scan wsum
  const int t = threadIdx.x;
  const int nBlk = gridDim.x;

  // ---- S1: hist zero | x convert | W pack | mark/compact (concurrent) ----
  const int V1 = histZB + convNB + 33 + markNB;
  for (int vb = blockIdx.x; vb < V1; vb += nBlk) {
    int s = vb;
    if (s < histZB) {
      ((int4*)hist)[s * 256 + t] = make_int4(0, 0, 0, 0);
    } else if ((s -= histZB) < convNB) {
      d_convert(x, xb, s * 256 + t, n4);
    } else if ((s -= convNB) < 33) {
      d_pack(W, Wroot, wp, wrootp, s, t, shm);
    } else {
      s -= 33;
      d_mark(head, tail, map, inv, cnt, s * 256 + t, T);
    }
  }
  gsync(bar, 0, nBlk);
  // ---- S2: histogram ----
  const int histNB = (E + 255) >> 8;
  for (int vb = blockIdx.x; vb < histNB; vb += nBlk)
    d_histe(ei, et, map, hist, vb * 256 + t, E);
  gsync(bar, 1, nBlk);
  // ---- S3: per-tile scan ----
  for (int vb = blockIdx.x; vb < NB2; vb += nBlk)
    d_scan(hist, offs, vb, t, (int*)shm);
  gsync(bar, 2, nBlk);
  // ---- S4: scatter ----
  for (int vb = blockIdx.x; vb < histNB; vb += nBlk)
    d_scat(ei, et, map, offs, sorted, vb * 256 + t, E);
  gsync(bar, 3, nBlk);
  // ---- S5: batch (tile x relation-group); grid == NB2*NSPLIT exactly ----
  for (int vb = blockIdx.x; vb < NB2 * NSPLIT; vb += nBlk)
    d_batch(xb, wp, wrootp, bias, sorted, offs, inv, cnt, h, vb, t, (u16*)shm);
  gsync(bar, 4, nBlk);
  // ---- S6: score (merge planes + relu) ----
  const int scNB = (T + 3) >> 2;
  for (int vb = blockIdx.x; vb < scNB; vb += nBlk)
    d_score(h, rel_emb, map, head, tail, rel, out, vb * 4 + (t >> 6), t & 63, T);
}

extern "C" void kernel_launch(void* const* d_in, const int* in_sizes, int n_in,
                              void* d_out, int out_size, void* d_ws, size_t ws_size,
                              hipStream_t stream) {
  const float* x     = (const float*)d_in[0];
  const float* W     = (const float*)d_in[1];
  const float* Wroot = (const float*)d_in[2];
  const float* bias  = (const float*)d_in[3];
  const float* relE  = (const float*)d_in[4];
  const int* ei      = (const int*)d_in[5];
  const int* et      = (const int*)d_in[6];
  const int* headI   = (const int*)d_in[7];
  const int* tailI   = (const int*)d_in[8];
  const int* relI    = (const int*)d_in[9];
  float* out = (float*)d_out;

  const int N = in_sizes[0] / 128;   // 50000
  const int E = in_sizes[6];         // 600000
  const int T = in_sizes[7];         // 8192
  const int NB2 = MAXU / 64;         // 256 compact tiles (worst case)
  const int NKEYS2 = NB2 * KEYS_PER_B;

  char* p = (char*)d_ws;
  auto alloc = [&](size_t bytes) -> void* {
    void* r = (void*)p;
    p += (bytes + 255) & ~(size_t)255;
    return r;
  };
  u16* xb     = (u16*)alloc((size_t)N * 128 * 2);           // 12.8 MB
  u16* wp     = (u16*)alloc((size_t)32 * 2048 * 8 * 2);     // 1 MB
  u16* wrootp = (u16*)alloc((size_t)2048 * 8 * 2);
  int* hist   = (int*)alloc((size_t)NKEYS2 * 4);            // 2 MB (zeroed in S1)
  int* map    = (int*)alloc((size_t)(N + 192) * 4);         // map + cnt + bar: one 0xFF fill
  int* cnt    = map + N;                                    // init -1
  int* bar    = map + N + 64;                               // init -1 per slot
  int* inv    = (int*)alloc((size_t)MAXU * 4);              // 64 KB
  int* offs   = (int*)alloc((size_t)NKEYS2 * 4);            // 2 MB
  u32* sorted = (u32*)alloc((size_t)NB2 * SORT_STRIDE * 4); // 1 MB
  float* h    = (float*)alloc((size_t)NSPLIT * MAXU * 128 * 4); // 33.5 MB

  const int n4 = N * 128 / 4;
  const int convNB = (n4 + 255) / 256;
  const int histZB = NKEYS2 / 1024;          // int4 x 256 per block
  const int markNB = (2 * T + 255) / 256;

  hipMemsetAsync(map, 0xFF, (size_t)(N + 192) * 4, stream);  // map/cnt/bar = -1
  k_fused<<<GRID, 256, 0, stream>>>(
      x, W, Wroot, xb, wp, wrootp, ei, et, headI, tailI, relI,
      map, inv, cnt, hist, offs, sorted, bias, h, relE, out, bar,
      n4, convNB, histZB, markNB, E, T, NB2);
}

// Round 10
// 187.502 us; speedup vs baseline: 7.7208x; 7.7208x over previous
//
#include <hip/hip_runtime.h>
#include <hip/hip_bf16.h>

typedef unsigned int u32;
typedef unsigned short u16;
typedef short short8 __attribute__((ext_vector_type(8)));
typedef float f32x4 __attribute__((ext_vector_type(4)));

#define R_ 32
#define KEYS_PER_B 2048     // 4 wavegroups * 32 relations * 16 rows
#define SORT_STRIDE 1024    // per-tile slots in sorted[] (mean ~656, large margin)
#define CAP 12              // per-wave per-relation buffered gathers (mean 5.1)
#define MAXU 16384          // max unique scored nodes (2*T)
#define NSPLIT 4            // relation-group split
#define NRG 8               // relations per group (R_/NSPLIT)

static __device__ __forceinline__ u16 f2bf(float f) {
  u32 u = __float_as_uint(f);
  u = (u + 0x7FFFu + ((u >> 16) & 1u)) >> 16;   // RNE
  return (u16)u;
}
static __device__ __forceinline__ u32 pk2(float a, float b) {
  __hip_bfloat162 h2 = __float22bfloat162_rn(make_float2(a, b));
  union { __hip_bfloat162 h; u32 u; } cv; cv.h = h2; return cv.u;
}

// key over COMPACT target ids: (tile, wavegroup-of-16, relation, row-in-group)
static __device__ __forceinline__ int sort_key(int ct, int r) {
  return (ct >> 6) * KEYS_PER_B + ((ct >> 4) & 3) * 512 + r * 16 + (ct & 15);
}

// ---- K1: x convert + W pack (LDS transpose) + hist zero + mark/compact ----
// map pre-filled -1, cnt pre-filled -1 (one 0xFF memset).
__global__ __launch_bounds__(256) void k_prep(
    const float* __restrict__ x, const float* __restrict__ W,
    const float* __restrict__ Wroot, u16* __restrict__ xb,
    u16* __restrict__ wp, u16* __restrict__ wrootp,
    const int* __restrict__ head, const int* __restrict__ tail,
    int* __restrict__ map, int* __restrict__ inv, int* __restrict__ cnt,
    int* __restrict__ hist, int n4, int convNB, int histZB, int T) {
  __shared__ u32 lds[8192];   // 32 KB: one 128x128 bf16 matrix
  int bx = blockIdx.x;
  const int t = threadIdx.x;
  if (bx < convNB) {
    int i = bx * 256 + t;
    if (i >= n4) return;
    const float4 f = ((const float4*)x)[i];
    u32 lo = (u32)f2bf(f.x) | ((u32)f2bf(f.y) << 16);
    u32 hi = (u32)f2bf(f.z) | ((u32)f2bf(f.w) << 16);
    ((uint2*)xb)[i] = make_uint2(lo, hi);
    return;
  }
  bx -= convNB;
  if (bx < 33) {
    const int rr = bx;
    const float* src = (rr < 32) ? (W + (size_t)rr * (128 * 128)) : Wroot;
#pragma unroll
    for (int k = 0; k < 16; ++k) {
      const int fi = k * 256 + t;
      const float4 f = ((const float4*)src)[fi];
      u32 lo = (u32)f2bf(f.x) | ((u32)f2bf(f.y) << 16);
      u32 hi = (u32)f2bf(f.z) | ((u32)f2bf(f.w) << 16);
      ((uint2*)lds)[fi] = make_uint2(lo, hi);
    }
    __syncthreads();
    const u16* l16 = (const u16*)lds;
#pragma unroll
    for (int p = 0; p < 8; ++p) {
      const int v = p * 256 + t;
      const int lane = v & 63, ks = (v >> 6) & 3, ct = v >> 8;
      const int i0 = ks * 32 + (lane >> 4) * 8;
      const int o  = ct * 16 + (lane & 15);
      u32 w01 = (u32)l16[(i0 + 0) * 128 + o] | ((u32)l16[(i0 + 1) * 128 + o] << 16);
      u32 w23 = (u32)l16[(i0 + 2) * 128 + o] | ((u32)l16[(i0 + 3) * 128 + o] << 16);
      u32 w45 = (u32)l16[(i0 + 4) * 128 + o] | ((u32)l16[(i0 + 5) * 128 + o] << 16);
      u32 w67 = (u32)l16[(i0 + 6) * 128 + o] | ((u32)l16[(i0 + 7) * 128 + o] << 16);
      u16* dst = (rr < 32) ? (wp + ((size_t)((rr * 8 + ct) * 4 + ks) * 64 + lane) * 8)
                           : (wrootp + ((size_t)((ct * 4 + ks) * 64 + lane)) * 8);
      *(uint4*)dst = make_uint4(w01, w23, w45, w67);
    }
    return;
  }
  bx -= 33;
  if (bx < histZB) {
    ((int4*)hist)[bx * 256 + t] = make_int4(0, 0, 0, 0);
    return;
  }
  bx -= histZB;
  int i = bx * 256 + t;
  if (i >= 2 * T) return;
  int n = (i < T) ? head[i] : tail[i - T];
  if (atomicCAS(map + n, -1, -2) == -1) {
    int c = atomicAdd(cnt, 1) + 1;   // cnt starts at -1 -> first ticket 0
    inv[c] = n;
    map[n] = c;
  }
}

// ---- K2: histogram of sort keys over KEPT edges (target used) ----
__global__ void k_hist(const int* __restrict__ ei, const int* __restrict__ et,
                       const int* __restrict__ map, int* __restrict__ hist, int E) {
  int e = blockIdx.x * 256 + threadIdx.x;
  if (e >= E) return;
  int mt = map[ei[E + e]];
  if (mt >= 0) atomicAdd(hist + sort_key(mt, et[e]), 1);
}

// ---- K3: per-tile exclusive scan (2048 keys per tile) ----
__global__ __launch_bounds__(256) void k_scan_local(const int* __restrict__ hist,
                                                    int* __restrict__ offs) {
  __shared__ int wsum[4];
  int b = blockIdx.x, t = threadIdx.x;
  size_t base = (size_t)b * KEYS_PER_B + (size_t)t * 8;
  int4 a = *(const int4*)(hist + base);
  int4 c = *(const int4*)(hist + base + 4);
  int v[8] = {a.x, a.y, a.z, a.w, c.x, c.y, c.z, c.w};
  int s = 0;
#pragma unroll
  for (int i = 0; i < 8; ++i) s += v[i];
  int lane = t & 63, w = t >> 6;
  int x = s;
#pragma unroll
  for (int off = 1; off < 64; off <<= 1) {
    int y = __shfl_up(x, off);
    if (lane >= off) x += y;
  }
  if (lane == 63) wsum[w] = x;
  __syncthreads();
  int wb = 0;
  for (int i = 0; i < w; ++i) wb += wsum[i];
  int ex = wb + x - s;
  int o[8];
#pragma unroll
  for (int i = 0; i < 8; ++i) { o[i] = ex; ex += v[i]; }
  *(int4*)(offs + base) = make_int4(o[0], o[1], o[2], o[3]);
  *(int4*)(offs + base + 4) = make_int4(o[4], o[5], o[6], o[7]);
}

// ---- K4: scatter kept edges; offs[key] -> per-key tile-local END ----
__global__ void k_scatter(const int* __restrict__ ei, const int* __restrict__ et,
                          const int* __restrict__ map,
                          int* __restrict__ offs, u32* __restrict__ sorted, int E) {
  int e = blockIdx.x * 256 + threadIdx.x;
  if (e >= E) return;
  int mt = map[ei[E + e]];
  if (mt < 0) return;
  int src = ei[e];
  int p = atomicAdd(offs + sort_key(mt, et[e]), 1);
  if (p < SORT_STRIDE)
    sorted[(size_t)(mt >> 6) * SORT_STRIDE + p] = (u32)src | ((u32)(mt & 63) << 16);
}

// ---- K5: batch kernel, ONE barrier per phase via double-buffered aggb ----
// Phase RI writes buf[RI&1]; GEMM(RI) reads buf[RI&1]. consume(RI+2)
// overwrites buf[RI&1] only after barrier B(RI+1), by which time every
// wave's GEMM(RI) is complete (program order: G(RI) < C(RI+1) < B(RI+1)).
// -> the trailing barrier of the old 2-barrier phase is removable.
// Gathers stay depth-2 prefetched; no vmcnt drain anywhere in the loop.
#define PHASE(RR, RI, XV, EVB)                                                 \
  {                                                                            \
    const int r = (RR);                                                        \
    u16* agg = aggb + ((RI) & 1) * (64 * 136);                                 \
    const int Er = __builtin_amdgcn_readlane(eAll, r);                         \
    _Pragma("unroll") for (int rr = 0; rr < 16; ++rr)                          \
        *(u32*)(agg + (size_t)(w * 16 + rr) * 136 + 2 * lane) = 0;             \
    {                                                                          \
      const int nB = min(Er - sCur, CAP);                                      \
      int curRow = -1, rc = 0;                                                 \
      float v0 = 0.f, v1 = 0.f;                                                \
      _Pragma("unroll") for (int j = 0; j < CAP; ++j) {                        \
        if (j < nB) {                                                          \
          int e = __builtin_amdgcn_readlane((int)(EVB), j);                    \
          int tl = (e >> 16) & 63;                                             \
          if (tl != curRow) {                                                  \
            if (rc > 0) {                                                      \
              float sc = __builtin_amdgcn_rcpf((float)rc);                     \
              *(u32*)(agg + (size_t)curRow * 136 + 2 * lane) =                 \
                  pk2(v0 * sc, v1 * sc);                                       \
            }                                                                  \
            curRow = tl; v0 = 0.f; v1 = 0.f; rc = 0;                           \
          }                                                                    \
          v0 += __uint_as_float((XV)[j] << 16);                                \
          v1 += __uint_as_float((XV)[j] & 0xFFFF0000u);                        \
          ++rc;                                                                \
        }                                                                      \
      }                                                                        \
      for (int p = sCur + CAP; p < Er; ++p) {                                  \
        u32 e = srt[p];                                                        \
        u32 xvv = *(const u32*)(xb + (size_t)(e & 0xFFFFu) * 128 + 2 * lane);  \
        int tl = (int)((e >> 16) & 63);                                        \
        if (tl != curRow) {                                                    \
          if (rc > 0) {                                                        \
            float sc = __builtin_amdgcn_rcpf((float)rc);                       \
            *(u32*)(agg + (size_t)curRow * 136 + 2 * lane) =                   \
                pk2(v0 * sc, v1 * sc);                                         \
          }                                                                    \
          curRow = tl; v0 = 0.f; v1 = 0.f; rc = 0;                             \
        }                                                                      \
        v0 += __uint_as_float(xvv << 16);                                      \
        v1 += __uint_as_float(xvv & 0xFFFF0000u);                              \
        ++rc;                                                                  \
      }                                                                        \
      if (rc > 0) {                                                            \
        float sc = __builtin_amdgcn_rcpf((float)rc);                           \
        *(u32*)(agg + (size_t)curRow * 136 + 2 * lane) =                       \
            pk2(v0 * sc, v1 * sc);                                             \
      }                                                                        \
    }                                                                          \
    asm volatile("s_waitcnt lgkmcnt(0)" ::: "memory");                         \
    __builtin_amdgcn_sched_barrier(0);                                         \
    __builtin_amdgcn_s_barrier();                                              \
    __builtin_amdgcn_sched_barrier(0);                                         \
    short8 bfr[4][2];                                                          \
    _Pragma("unroll") for (int ks = 0; ks < 4; ++ks)                           \
      _Pragma("unroll") for (int c = 0; c < 2; ++c)                            \
        bfr[ks][c] = *(const short8*)(wp +                                     \
            ((size_t)(((r * 8 + wct0 + c) * 4 + ks) * 64 + lane)) * 8);        \
    __builtin_amdgcn_sched_barrier(0);                                         \
    if ((RI) + 2 < NRG) {                                                      \
      const int sN = __builtin_amdgcn_readlane(eAll, r + 1);                   \
      const int eN = __builtin_amdgcn_readlane(eAll, r + 2);                   \
      (EVB) = ev2;                                                             \
      const int nBn = min(eN - sN, CAP);                                       \
      _Pragma("unroll") for (int j = 0; j < CAP; ++j) {                        \
        if (j < nBn) {                                                         \
          int e = __builtin_amdgcn_readlane((int)(EVB), j);                    \
          (XV)[j] = *(const u32*)(xb + (size_t)(e & 0xFFFF) * 128 + 2 * lane); \
        }                                                                      \
      }                                                                        \
      if ((RI) + 3 < NRG) {                                                    \
        int pcn = eN + m;                                                      \
        if (pcn > clampP) pcn = clampP;                                        \
        ev2 = srt[pcn];                                                        \
      }                                                                        \
    }                                                                          \
    _Pragma("unroll") for (int ks = 0; ks < 4; ++ks) {                         \
      const int kb = ks * 32 + q * 8;                                          \
      short8 af[4];                                                            \
      _Pragma("unroll") for (int rt = 0; rt < 4; ++rt)                         \
        af[rt] = *(const short8*)(agg + (size_t)(rt * 16 + m) * 136 + kb);     \
      _Pragma("unroll") for (int c = 0; c < 2; ++c)                            \
        _Pragma("unroll") for (int rt = 0; rt < 4; ++rt)                       \
          acc[rt][c] = __builtin_amdgcn_mfma_f32_16x16x32_bf16(                \
              af[rt], bfr[ks][c], acc[rt][c], 0, 0, 0);                        \
    }                                                                          \
    sCur = Er;                                                                 \
  }

__global__ __launch_bounds__(256) void k_batch(
    const u16* __restrict__ xb, const u16* __restrict__ wp, const u16* __restrict__ wrootp,
    const float* __restrict__ bias, const u32* __restrict__ sorted,
    const int* __restrict__ offs, const int* __restrict__ inv,
    const int* __restrict__ cnt, float* __restrict__ h) {
  __shared__ u16 aggb[2 * 64 * 136];   // 34.8 KB double buffer
  const int nUsed = cnt[0] + 1;        // cnt holds last ticket (init -1)
  const int qs = blockIdx.x & (NSPLIT - 1);
  const int b = blockIdx.x >> 2;
  const int t = threadIdx.x;
  const int nb = b * 64;
  if (nb >= nUsed) return;             // uniform: before any barrier
  const int r0 = qs * NRG;
  const int lane = t & 63, w = t >> 6;
  const int m = lane & 15, q = lane >> 4;
  const int keyBase = b * KEYS_PER_B;
  const int wkBase = keyBase + w * 512;
  const u32* srt = sorted + (size_t)b * SORT_STRIDE;

  const int nEdge = offs[keyBase + KEYS_PER_B - 1];
  const int clampP = (nEdge > 0) ? nEdge - 1 : 0;
  const int eAll = offs[wkBase + (lane & 31) * 16 + 15];   // lane r: end of rel r
  int sCur = (w == 0 && qs == 0) ? 0 : offs[wkBase + r0 * 16 - 1];

  const int E0 = __builtin_amdgcn_readlane(eAll, r0);
  const int E1 = __builtin_amdgcn_readlane(eAll, r0 + 1);

  u32 evBufA, evBufB, ev2;
  u32 xvA[CAP], xvB[CAP];
  {
    int pc = sCur + m;
    if (pc > clampP) pc = clampP;
    evBufA = srt[pc];
  }
  {
    const int nB = min(E0 - sCur, CAP);
#pragma unroll
    for (int j = 0; j < CAP; ++j) {
      if (j < nB) {
        int e = __builtin_amdgcn_readlane((int)evBufA, j);
        xvA[j] = *(const u32*)(xb + (size_t)(e & 0xFFFF) * 128 + 2 * lane);
      }
    }
  }
  {
    int pc = E0 + m;
    if (pc > clampP) pc = clampP;
    evBufB = srt[pc];
  }
  {
    const int nB = min(E1 - E0, CAP);
#pragma unroll
    for (int j = 0; j < CAP; ++j) {
      if (j < nB) {
        int e = __builtin_amdgcn_readlane((int)evBufB, j);
        xvB[j] = *(const u32*)(xb + (size_t)(e & 0xFFFF) * 128 + 2 * lane);
      }
    }
  }
  {
    int pc = E1 + m;
    if (pc > clampP) pc = clampP;
    ev2 = srt[pc];
  }

  const short8 zero8 = {0, 0, 0, 0, 0, 0, 0, 0};
  f32x4 acc[4][2];
#pragma unroll
  for (int rt = 0; rt < 4; ++rt)
#pragma unroll
    for (int c = 0; c < 2; ++c) acc[rt][c] = (f32x4){0.f, 0.f, 0.f, 0.f};
  const int wct0 = w * 2;

  // root GEMM only in plane 0
  if (qs == 0) {
    int nodeR[4]; bool vR[4];
#pragma unroll
    for (int rt = 0; rt < 4; ++rt) {
      int crow = nb + rt * 16 + m;
      vR[rt] = crow < nUsed;
      nodeR[rt] = inv[vR[rt] ? crow : (nUsed - 1)];
    }
#pragma unroll
    for (int ks = 0; ks < 4; ++ks) {
      const int kb = ks * 32 + q * 8;
      short8 af[4];
#pragma unroll
      for (int rt = 0; rt < 4; ++rt)
        af[rt] = vR[rt] ? *(const short8*)(xb + (size_t)nodeR[rt] * 128 + kb) : zero8;
#pragma unroll
      for (int c = 0; c < 2; ++c) {
        short8 bf = *(const short8*)(wrootp + ((size_t)(((wct0 + c) * 4 + ks) * 64 + lane)) * 8);
#pragma unroll
        for (int rt = 0; rt < 4; ++rt)
          acc[rt][c] = __builtin_amdgcn_mfma_f32_16x16x32_bf16(af[rt], bf, acc[rt][c], 0, 0, 0);
      }
    }
  }

  for (int ri = 0; ri < NRG; ri += 2) {
    PHASE(r0 + ri, ri, xvA, evBufA)
    PHASE(r0 + ri + 1, ri + 1, xvB, evBufB)
  }

  // epilogue: (+bias in plane 0) store RAW partial plane
  float* hq = h + (size_t)qs * MAXU * 128;
#pragma unroll
  for (int c = 0; c < 2; ++c) {
    const int col = (wct0 + c) * 16 + m;
    const float bv = (qs == 0) ? bias[col] : 0.f;
#pragma unroll
    for (int rt = 0; rt < 4; ++rt) {
#pragma unroll
      for (int g = 0; g < 4; ++g) {
        const int row = nb + rt * 16 + q * 4 + g;
        if (row < nUsed) hq[(size_t)row * 128 + col] = acc[rt][c][g] + bv;
      }
    }
  }
}

// ---- K6: DistMult scoring; merge 4 partial planes + relu ----
__global__ void k_score(const float* __restrict__ h, const float* __restrict__ rel_emb,
                        const int* __restrict__ map,
                        const int* __restrict__ head, const int* __restrict__ tail,
                        const int* __restrict__ rel, float* __restrict__ out, int T) {
  int lane = threadIdx.x & 63, w = threadIdx.x >> 6;
  int gid = blockIdx.x * 4 + w;
  if (gid >= T) return;
  const int hr = map[head[gid]];
  const int tr = map[tail[gid]];
  const size_t ho = (size_t)hr * 128 + 2 * lane;
  const size_t to = (size_t)tr * 128 + 2 * lane;
  float hx = 0.f, hy = 0.f, tx = 0.f, ty = 0.f;
#pragma unroll
  for (int s = 0; s < NSPLIT; ++s) {
    const float2 a = *(const float2*)(h + (size_t)s * (MAXU * 128) + ho);
    const float2 c = *(const float2*)(h + (size_t)s * (MAXU * 128) + to);
    hx += a.x; hy += a.y; tx += c.x; ty += c.y;
  }
  hx = hx > 0.f ? hx : 0.f;
  hy = hy > 0.f ? hy : 0.f;
  tx = tx > 0.f ? tx : 0.f;
  ty = ty > 0.f ? ty : 0.f;
  const float2 r2 = *(const float2*)(rel_emb + (size_t)rel[gid] * 128 + 2 * lane);
  float s = hx * r2.x * tx + hy * r2.y * ty;
#pragma unroll
  for (int off = 32; off > 0; off >>= 1) s += __shfl_down(s, off);
  if (lane == 0) out[gid] = s;
}

extern "C" void kernel_launch(void* const* d_in, const int* in_sizes, int n_in,
                              void* d_out, int out_size, void* d_ws, size_t ws_size,
                              hipStream_t stream) {
  const float* x     = (const float*)d_in[0];
  const float* W     = (const float*)d_in[1];
  const float* Wroot = (const float*)d_in[2];
  const float* bias  = (const float*)d_in[3];
  const float* relE  = (const float*)d_in[4];
  const int* ei      = (const int*)d_in[5];
  const int* et      = (const int*)d_in[6];
  const int* headI   = (const int*)d_in[7];
  const int* tailI   = (const int*)d_in[8];
  const int* relI    = (const int*)d_in[9];
  float* out = (float*)d_out;

  const int N = in_sizes[0] / 128;   // 50000
  const int E = in_sizes[6];         // 600000
  const int T = in_sizes[7];         // 8192
  const int NB2 = MAXU / 64;         // 256 compact tiles (worst case)
  const int NKEYS2 = NB2 * KEYS_PER_B;

  char* p = (char*)d_ws;
  auto alloc = [&](size_t bytes) -> void* {
    void* r = (void*)p;
    p += (bytes + 255) & ~(size_t)255;
    return r;
  };
  u16* xb     = (u16*)alloc((size_t)N * 128 * 2);           // 12.8 MB
  u16* wp     = (u16*)alloc((size_t)32 * 2048 * 8 * 2);     // 1 MB
  u16* wrootp = (u16*)alloc((size_t)2048 * 8 * 2);
  int* hist   = (int*)alloc((size_t)NKEYS2 * 4);            // 2 MB (zeroed in k_prep)
  int* map    = (int*)alloc((size_t)(N + 64) * 4);          // map + cnt, one 0xFF fill
  int* cnt    = map + N;
  int* inv    = (int*)alloc((size_t)MAXU * 4);              // 64 KB
  int* offs   = (int*)alloc((size_t)NKEYS2 * 4);            // 2 MB
  u32* sorted = (u32*)alloc((size_t)NB2 * SORT_STRIDE * 4); // 1 MB
  float* h    = (float*)alloc((size_t)NSPLIT * MAXU * 128 * 4); // 33.5 MB

  const int n4 = N * 128 / 4;
  const int convNB = (n4 + 255) / 256;
  const int histZB = NKEYS2 / 1024;          // int4 x 256 per block
  const int markNB = (2 * T + 255) / 256;

  hipMemsetAsync(map, 0xFF, (size_t)(N + 64) * 4, stream);   // map=-1, cnt=-1
  k_prep<<<convNB + 33 + histZB + markNB, 256, 0, stream>>>(
      x, W, Wroot, xb, wp, wrootp, headI, tailI, map, inv, cnt, hist,
      n4, convNB, histZB, T);
  k_hist<<<(E + 255) / 256, 256, 0, stream>>>(ei, et, map, hist, E);
  k_scan_local<<<NB2, 256, 0, stream>>>(hist, offs);
  k_scatter<<<(E + 255) / 256, 256, 0, stream>>>(ei, et, map, offs, sorted, E);
  k_batch<<<NB2 * NSPLIT, 256, 0, stream>>>(xb, wp, wrootp, bias, sorted, offs, inv, cnt, h);
  k_score<<<(T + 3) / 4, 256, 0, stream>>>(h, relE, map, headI, tailI, relI, out, T);
}